// Round 20
// baseline (118.908 us; speedup 1.0000x reference)
//
#include <hip/hip_runtime.h>

// ---------------- problem constants ----------------
#define T_LEN   2048
#define BATCH   2
#define DMODEL  1024
#define NHEAD   16
#define DHEAD   64
#define MROWS   4096          // T*B
#define KDIM    1024
#define NDIM    1024
#define ATT_SC2 (0.125f * 1.44269504088896f)   // SCALE * log2(e), folded into Wq

typedef unsigned short u16;
typedef unsigned int   u32;
typedef u16   u16x8 __attribute__((ext_vector_type(8)));
typedef u16   u16x4 __attribute__((ext_vector_type(4)));
typedef __bf16 bf16x8 __attribute__((ext_vector_type(8)));
typedef float f32x4 __attribute__((ext_vector_type(4)));

__device__ __forceinline__ u16 f2bf(float f) {
  u32 u = __builtin_bit_cast(u32, f);
  u += 0x7fffu + ((u >> 16) & 1u);           // round-to-nearest-even
  return (u16)(u >> 16);
}

__device__ __forceinline__ u16 bfc(float f) {  // compiler cvt (packs to cvt_pk)
  return __builtin_bit_cast(u16, (__bf16)f);
}

__device__ __forceinline__ f32x4 mfma16(u16x8 a, u16x8 b, f32x4 c) {
  return __builtin_amdgcn_mfma_f32_16x16x32_bf16(
      __builtin_bit_cast(bf16x8, a), __builtin_bit_cast(bf16x8, b), c, 0, 0, 0);
}

__device__ __forceinline__ void gload16(const u16* g, u16* l) {
  __builtin_amdgcn_global_load_lds((const __attribute__((address_space(1))) void*)g,
                                   (__attribute__((address_space(3))) void*)l,
                                   16, 0, 0);
}

// ---------------- cast f32 -> bf16 with layout fixes (r12 version) ----------------
// ws (u16): [xbm 4M][Wqkv 3M: rows 0..1023 Wq | 1024..2047 Wk | 2048..3071 Wv]
//           [Wob 1M][Qh 4M][Kh 4M][Vt 4M][Aout 4M]
#define XN 4194304u
__global__ __launch_bounds__(256) void cast_all(
    const float* __restrict__ x,  const float* __restrict__ wk,
    const float* __restrict__ wv, const float* __restrict__ wq,
    const float* __restrict__ wo, u16* __restrict__ ws) {
  size_t i = ((size_t)blockIdx.x * 256 + threadIdx.x) * 4;
  const float* src; size_t soff, doff; float sc = 1.0f;
  if (i < XN) {
    int m = (int)(i >> 10), d = (int)(i & 1023);
    int t = m >> 1, b = m & 1;
    src = x; soff = i;
    doff = ((size_t)(b * 2048 + t) << 10) + d;
  } else {
    size_t off = i - XN;
    int wi = (int)(off >> 20);
    off &= 1048575u;
    int u = (int)(off >> 10), c = (int)(off & 1023);
    src = (wi == 0) ? wk : (wi == 1) ? wv : (wi == 2) ? wq : wo;
    soff = off;
    if (wi == 3) {
      doff = XN + 3u * 1048576u + off;                      // Wob linear
    } else {
      int slot = (wi == 2) ? 0 : (wi == 0) ? 1 : 2;         // Q,K,V pack order
      int up = (u & 15) * 64 + (u >> 4);                    // head-outer perm
      doff = XN + (size_t)slot * 1048576u + ((size_t)up << 10) + c;
      if (wi == 2) sc = ATT_SC2;
    }
  }
  float4 v = *reinterpret_cast<const float4*>(src + soff);
  u16x4 o;
  o.s0 = f2bf(v.x * sc); o.s1 = f2bf(v.y * sc); o.s2 = f2bf(v.z * sc); o.s3 = f2bf(v.w * sc);
  *reinterpret_cast<u16x4*>(ws + doff) = o;
}

// ---------------- QKV GEMM: 256x128 tile, BK=64, per-wave 128x64 (r12) ----------------
__global__ __launch_bounds__(256, 2) void gemm_qkv(
    const u16* __restrict__ xbm, const u16* __restrict__ Wqkv,
    u16* __restrict__ Qh, u16* __restrict__ Kh, u16* __restrict__ Vt) {
  __shared__ __align__(16) u16 As[256 * 64];   // 32 KB
  __shared__ __align__(16) u16 Bs[128 * 64];   // 16 KB

  const int tid = threadIdx.x;
  const int l  = tid & 63, w = tid >> 6;
  const int lr = l & 15,  lg = l >> 4;
  const int wm = w >> 1,  wn = w & 1;

  const int blk  = blockIdx.x;
  const int wgid = (blk & 7) * 48 + (blk >> 3);   // bijective (384 % 8 == 0)

  const u16 *A, *W;
  int m0, n0, isV;
  if (wgid < 256) {
    const int bx = wgid >> 4, by = wgid & 15;
    A = xbm; W = Wqkv; m0 = by * 256; n0 = bx * 128; isV = 0;
  } else {
    const int v = wgid - 256;
    const int vby = v >> 5, vbx = v & 31;
    A = Wqkv + (2048u << 10); W = xbm; m0 = vby * 256; n0 = vbx * 128; isV = 1;
  }

  f32x4 acc[8][4];
#pragma unroll
  for (int i = 0; i < 8; ++i)
#pragma unroll
    for (int j = 0; j < 4; ++j) acc[i][j] = (f32x4)(0.0f);

  for (int k0 = 0; k0 < KDIM; k0 += 64) {
#pragma unroll
    for (int i = 0; i < 8; ++i) {
      const int base = i * 256 + w * 64;
      const int p = base + l;
      const int r = p >> 3, c = p & 7;
      gload16(A + (size_t)(m0 + r) * KDIM + k0 + ((c ^ (r & 7)) << 3),
              As + (size_t)base * 8);
    }
#pragma unroll
    for (int i = 0; i < 4; ++i) {
      const int base = i * 256 + w * 64;
      const int p = base + l;
      const int r = p >> 3, c = p & 7;
      gload16(W + (size_t)(n0 + r) * KDIM + k0 + ((c ^ (r & 7)) << 3),
              Bs + (size_t)base * 8);
    }
    __syncthreads();

#pragma unroll
    for (int ks = 0; ks < 2; ++ks) {
      const int cr = ks * 4 + lg;
      u16x8 bf_[4];
#pragma unroll
      for (int ni = 0; ni < 4; ++ni) {
        const int rr = wn * 64 + ni * 16 + lr;
        bf_[ni] = *reinterpret_cast<const u16x8*>(Bs + rr * 64 + ((cr ^ (rr & 7)) << 3));
      }
      __builtin_amdgcn_s_setprio(1);
#pragma unroll
      for (int mi = 0; mi < 8; ++mi) {
        const int rr = wm * 128 + mi * 16 + lr;
        const u16x8 af = *reinterpret_cast<const u16x8*>(
            As + rr * 64 + ((cr ^ (rr & 7)) << 3));
#pragma unroll
        for (int ni = 0; ni < 4; ++ni)
          acc[mi][ni] = mfma16(af, bf_[ni], acc[mi][ni]);
      }
      __builtin_amdgcn_s_setprio(0);
    }
    __syncthreads();
  }

#pragma unroll
  for (int mi = 0; mi < 8; ++mi)
#pragma unroll
    for (int ni = 0; ni < 4; ++ni)
#pragma unroll
      for (int r = 0; r < 4; ++r) {
        const int row = m0 + wm * 128 + mi * 16 + lg * 4 + r;
        const int col = n0 + wn * 64 + ni * 16 + lr;
        const u16 v = bfc(acc[mi][ni][r]);
        if (!isV) {
          const int bb = row >> 11, t = row & 2047;
          const int c = col & 1023, hh = c >> 6, dp = c & 63;
          u16* d = (col < 1024) ? Qh : Kh;
          d[(((size_t)(bb * NHEAD + hh) << 11) + t) * 64 + dp] = v;
        } else {
          const int hh = row >> 6, dp = row & 63;
          const int bb = col >> 11, t = col & 2047;
          Vt[((((size_t)(bb * NHEAD + hh)) * 64 + dp) << 11) + t] = v;
        }
      }
}

// ---------------- O projection: 128x64 tile, 512 blocks (grid-rich) ----------------
__global__ __launch_bounds__(256) void gemm_o(
    const u16* __restrict__ A, const u16* __restrict__ W, float* __restrict__ out) {
  __shared__ __align__(16) u16 As[128 * 64];   // 16 KB
  __shared__ __align__(16) u16 Bs[64 * 64];    // 8 KB

  const int tid = threadIdx.x;
  const int l  = tid & 63, w = tid >> 6;
  const int lr = l & 15,  lg = l >> 4;
  const int wm = w >> 1,  wn = w & 1;

  const int blk  = blockIdx.x;
  const int wgid = (blk & 7) * 64 + (blk >> 3);   // bijective (512 % 8 == 0)
  const int bx = wgid >> 5, by = wgid & 31;       // same-bx grouped per XCD
  const int m0 = by * 128;
  const int n0 = bx * 64;

  f32x4 acc[4][2];
#pragma unroll
  for (int i = 0; i < 4; ++i)
#pragma unroll
    for (int j = 0; j < 2; ++j) acc[i][j] = (f32x4)(0.0f);

  for (int k0 = 0; k0 < KDIM; k0 += 64) {
#pragma unroll
    for (int i = 0; i < 4; ++i) {                 // A: 1024 chunks
      const int base = i * 256 + w * 64;
      const int p = base + l;
      const int r = p >> 3, c = p & 7;
      gload16(A + (size_t)(m0 + r) * KDIM + k0 + ((c ^ (r & 7)) << 3),
              As + (size_t)base * 8);
    }
#pragma unroll
    for (int i = 0; i < 2; ++i) {                 // B: 512 chunks
      const int base = i * 256 + w * 64;
      const int p = base + l;
      const int r = p >> 3, c = p & 7;
      gload16(W + (size_t)(n0 + r) * KDIM + k0 + ((c ^ (r & 7)) << 3),
              Bs + (size_t)base * 8);
    }
    __syncthreads();

#pragma unroll
    for (int ks = 0; ks < 2; ++ks) {
      const int cr = ks * 4 + lg;
      u16x8 bf_[2];
#pragma unroll
      for (int ni = 0; ni < 2; ++ni) {
        const int rr = wn * 32 + ni * 16 + lr;
        bf_[ni] = *reinterpret_cast<const u16x8*>(Bs + rr * 64 + ((cr ^ (rr & 7)) << 3));
      }
      __builtin_amdgcn_s_setprio(1);
#pragma unroll
      for (int mi = 0; mi < 4; ++mi) {
        const int rr = wm * 64 + mi * 16 + lr;
        const u16x8 af = *reinterpret_cast<const u16x8*>(
            As + rr * 64 + ((cr ^ (rr & 7)) << 3));
#pragma unroll
        for (int ni = 0; ni < 2; ++ni)
          acc[mi][ni] = mfma16(af, bf_[ni], acc[mi][ni]);
      }
      __builtin_amdgcn_s_setprio(0);
    }
    __syncthreads();
  }

#pragma unroll
  for (int mi = 0; mi < 4; ++mi)
#pragma unroll
    for (int ni = 0; ni < 2; ++ni)
#pragma unroll
      for (int r = 0; r < 4; ++r) {
        const int row = m0 + wm * 64 + mi * 16 + lg * 4 + r;  // b*2048+t
        const int col = n0 + wn * 32 + ni * 16 + lr;
        const int t = row & 2047, bb = row >> 11;
        out[((size_t)(t * 2 + bb) << 10) + col] = acc[mi][ni][r];
      }
}

// ---------------- causal flash attention v18: kv-128, 8-wave, 4/SIMD ----------------
// 512 threads: wq{0,1} owns 32 q-rows (2 groups of 16), wk{0..3} owns a 32-kv
// quarter of each kv-128 tile -> kf/vf fragments serve 2 q-groups each.
// LDS 74 KB (Ks dbuf 32K + Vs dbuf 32K + Pw 10K) -> 2 blocks/CU x 8 waves =
// 4 waves/SIMD. Counted-vmcnt(4) raw barriers (~35 barriers/block, half of
// v17). Padded Pw rows (40 u16, no XOR -> 2-way max). Fixed-shift softmax,
// 4-way wk-combine per phase via dead-LDS.
__global__ __launch_bounds__(512, 2) void attn_fwd(
    const u16* __restrict__ Qh, const u16* __restrict__ Kh,
    const u16* __restrict__ Vt, u16* __restrict__ Aout) {
  // u16 carve: Ks[2][8192]=0..16383 | Vs[2][8192]=16384..32767 | Pw 8x640=32768..37887
  __shared__ __align__(16) u16 smem[37888];

  const int tid = threadIdx.x;
  const int l = tid & 63, w = tid >> 6;           // w 0..7
  const int lr = l & 15, lg = l >> 4;
  const int wk = w & 3, wq = w >> 2;              // wk 0..3, wq 0..1
  const int blk = blockIdx.x;
  const int bxx = (blk >> 3) & 15;
  const int bh  = ((blk >> 7) << 3) + (blk & 7);  // XCD-grouped heads
  const int b = bh >> 4, h = bh & 15;

  const u16* kg = Kh + ((size_t)bh << 17);    // [t][64]
  const u16* vg = Vt + ((size_t)bh << 17);    // [64][2048]
  u16* Pw = smem + 32768 + w * 640;           // per-wave P tile [16 q][40 pad]

  float* redO = reinterpret_cast<float*>(smem);            // 6 x [32 q][68] = 52224 B
  float* redS = reinterpret_cast<float*>(smem + 32768);    // 192 floats over dead Pw

  const u16x8 ones = {0x3F80,0x3F80,0x3F80,0x3F80,0x3F80,0x3F80,0x3F80,0x3F80};

  auto stage = [&](int buf, int kv0) {        // K 1024 + V 1024 chunks; 2 each/thread
    u16* kb = smem + buf * 8192;
    u16* vb = smem + 16384 + buf * 8192;
#pragma unroll
    for (int j = 0; j < 2; ++j) {
      const int base = (j * 8 + w) * 64;      // chunk base (wave-uniform)
      const int gg = base + l;
      const int rk = gg >> 3, ck = gg & 7;    // K: 8 chunks/row (128 rows)
      gload16(kg + (size_t)(kv0 + rk) * 64 + ((ck ^ (rk & 7)) << 3),
              kb + (size_t)base * 8);
      const int rv = gg >> 4, cv = gg & 15;   // V: 16 chunks/row (64 rows)
      gload16(vg + ((size_t)rv << 11) + kv0 + ((cv ^ (rv & 15)) << 3),
              vb + (size_t)base * 8);
    }
  };

  for (int ph = 0; ph < 2; ++ph) {
    const int qb = ph ? bxx : 31 - bxx;
    const int qbw = qb * 64 + wq * 32;        // wave's 32-q window start

    u16x8 qf[2][2];
#pragma unroll
    for (int g = 0; g < 2; ++g) {
      const int qrow = qbw + g * 16 + lr;
      const u16* qptr = Qh + (((size_t)bh << 11) + qrow) * 64 + lg * 8;
      qf[g][0] = *reinterpret_cast<const u16x8*>(qptr);
      qf[g][1] = *reinterpret_cast<const u16x8*>(qptr + 32);
    }

    f32x4 oacc[2][4];
#pragma unroll
    for (int g = 0; g < 2; ++g)
#pragma unroll
      for (int i = 0; i < 4; ++i) oacc[g][i] = (f32x4)(0.0f);
    f32x4 sum4[2] = {(f32x4)(0.0f), (f32x4)(0.0f)};

    const int npair = (qb + 2) >> 1;          // kv-128 tiles
    stage(0, 0);
    __syncthreads();                           // prologue: full drain ok

    int cur = 0;
    for (int t = 0; t < npair; ++t) {
      const int kv0 = t * 128;
      const bool pf = (t + 1 < npair);
      if (pf) {
        stage(cur ^ 1, kv0 + 128);             // issue 4 loads, keep in flight
        asm volatile("s_waitcnt vmcnt(4)" ::: "memory");   // tile t ready
      } else {
        asm volatile("s_waitcnt vmcnt(0)" ::: "memory");
      }
      __builtin_amdgcn_sched_barrier(0);
      __builtin_amdgcn_s_barrier();            // all waves: tile t ready

      const int kvw = kv0 + wk * 32;          // wave's 32-kv window start
      if (kvw <= qbw + 31) {                  // wave has live work
        const u16* kb = smem + cur * 8192;
        const u16* vb = smem + 16384 + cur * 8192;

        // hoisted K/V fragments (shared across both q-groups)
        u16x8 kf[2][2];
#pragma unroll
        for (int tt = 0; tt < 2; ++tt) {
          const int row = wk * 32 + tt * 16 + lr;
          kf[tt][0] = *reinterpret_cast<const u16x8*>(
              kb + row * 64 + ((lg ^ (row & 7)) << 3));
          kf[tt][1] = *reinterpret_cast<const u16x8*>(
              kb + row * 64 + (((4 + lg) ^ (row & 7)) << 3));
        }
        u16x8 vf[4];
#pragma unroll
        for (int ni = 0; ni < 4; ++ni) {
          const int dr = ni * 16 + lr;
          const int ck = wk * 4 + lg;
          vf[ni] = *reinterpret_cast<const u16x8*>(
              vb + dr * 128 + ((ck ^ (dr & 15)) << 3));
        }

#pragma unroll
        for (int g = 0; g < 2; ++g) {
          const int qbg = qbw + g * 16;
          if (kvw <= qbg + 15) {              // group live for this window
            const bool diag = (kvw + 31 > qbg);
            const int qrow = qbg + lr;

            // ---- QK^T -> mask -> exp2(S-8) -> pack -> Pw (per tt)
            __builtin_amdgcn_s_setprio(1);
#pragma unroll
            for (int tt = 0; tt < 2; ++tt) {
              f32x4 sacc = (f32x4)(0.0f);
              sacc = mfma16(kf[tt][0], qf[g][0], sacc);
              sacc = mfma16(kf[tt][1], qf[g][1], sacc);
              u16x4 pk;
#pragma unroll
              for (int r = 0; r < 4; ++r) {
                const int kv = kvw + tt * 16 + lg * 4 + r;
                const float s = (diag && kv > qrow) ? -1e30f : sacc[r];
                pk[r] = bfc(__builtin_amdgcn_exp2f(s - 8.0f));
              }
              // row lr (stride 40 u16), col kv = tt*16 + lg*4 : padded, no XOR
              *reinterpret_cast<u16x4*>(&Pw[lr * 40 + tt * 16 + lg * 4]) = pk;
            }

            // ---- PV + MFMA row-sum over the 32-kv window (K=32, one A-frag)
            {
              const u16x8 pa = *reinterpret_cast<const u16x8*>(&Pw[lr * 40 + lg * 8]);
              sum4[g] = mfma16(pa, ones, sum4[g]);   // row-sum in O's C-layout
#pragma unroll
              for (int ni = 0; ni < 4; ++ni)
                oacc[g][ni] = mfma16(pa, vf[ni], oacc[g][ni]);
            }
            __builtin_amdgcn_s_setprio(0);
          }
        }
      }

      asm volatile("s_waitcnt lgkmcnt(0)" ::: "memory");   // done reading cur
      __builtin_amdgcn_sched_barrier(0);
      __builtin_amdgcn_s_barrier();            // cur may be overwritten
      cur ^= 1;
    }

    // ---- 4-way wk combine: wk=1,2,3 publish partials, wk=0 adds + stores.
    if (wk) {
      float* po = redO + (wq * 3 + wk - 1) * 2176;   // [32 q][stride 68]
#pragma unroll
      for (int g = 0; g < 2; ++g) {
#pragma unroll
        for (int ni = 0; ni < 4; ++ni)
#pragma unroll
          for (int r = 0; r < 4; ++r)
            po[(g * 16 + lg * 4 + r) * 68 + ni * 16 + lr] = oacc[g][ni][r];
        if (lr == 0) {
#pragma unroll
          for (int r = 0; r < 4; ++r)
            redS[(wq * 3 + wk - 1) * 32 + g * 16 + lg * 4 + r] = sum4[g][r];
        }
      }
    }
    __syncthreads();

    if (!wk) {
#pragma unroll
      for (int g = 0; g < 2; ++g) {
        f32x4 ss = sum4[g];
#pragma unroll
        for (int j = 0; j < 3; ++j)
#pragma unroll
          for (int r = 0; r < 4; ++r)
            ss[r] += redS[(wq * 3 + j) * 32 + g * 16 + lg * 4 + r];
#pragma unroll
        for (int r = 0; r < 4; ++r) {
          const float inv = 1.0f / ss[r];
          const int q = qbw + g * 16 + lg * 4 + r;
          const size_t rowbase = (((size_t)(b * 2048 + q)) << 10) + h * DHEAD;
#pragma unroll
          for (int ni = 0; ni < 4; ++ni) {
            float o = oacc[g][ni][r];
#pragma unroll
            for (int j = 0; j < 3; ++j)
              o += redO[(wq * 3 + j) * 2176 + (g * 16 + lg * 4 + r) * 68 + ni * 16 + lr];
            Aout[rowbase + ni * 16 + lr] = bfc(o * inv);
          }
        }
      }
    }
    __syncthreads();   // redO/redS (aliased on Ks/Vs/Pw) free before next stage
  }
}

// ---------------- launch ----------------
extern "C" void kernel_launch(void* const* d_in, const int* in_sizes, int n_in,
                              void* d_out, int out_size, void* d_ws, size_t ws_size,
                              hipStream_t stream) {
  const float* x  = (const float*)d_in[0];
  const float* Wk = (const float*)d_in[1];
  const float* Wv = (const float*)d_in[2];
  const float* Wq = (const float*)d_in[3];
  const float* Wo = (const float*)d_in[4];
  // d_in[5] = mask (causal, known structurally)

  u16* ws   = (u16*)d_ws;
  u16* xbm  = ws;                      // 4M  [b*2048+t][d]
  u16* Wqkv = xbm + 4194304;           // 3M  [Wq|Wk|Wv], head-perm rows
  u16* Wob  = Wqkv + 3145728;          // 1M
  u16* Qh   = Wob + 1048576;           // 4M  [bh][t][64]
  u16* Kh   = Qh  + 4194304;           // 4M  [bh][t][64]
  u16* Vt   = Kh  + 4194304;           // 4M  [bh][64][t]
  u16* Aout = Vt  + 4194304;           // 4M  [b*2048+t][h*64+dp]

  cast_all<<<8192, 256, 0, stream>>>(x, Wk, Wv, Wq, Wo, ws);

  gemm_qkv<<<384, 256, 0, stream>>>(xbm, Wqkv, Qh, Kh, Vt);

  attn_fwd<<<512, 512, 0, stream>>>(Qh, Kh, Vt, Aout);

  gemm_o<<<512, 256, 0, stream>>>(Aout, Wob, (float*)d_out);
}

// Round 21
// 104.732 us; speedup vs baseline: 1.1354x; 1.1354x over previous
//
#include <hip/hip_runtime.h>

// ---------------- problem constants ----------------
#define T_LEN   2048
#define BATCH   2
#define DMODEL  1024
#define NHEAD   16
#define DHEAD   64
#define MROWS   4096          // T*B
#define KDIM    1024
#define NDIM    1024
#define ATT_SC2 (0.125f * 1.44269504088896f)   // SCALE * log2(e), folded into Wq

typedef unsigned short u16;
typedef unsigned int   u32;
typedef u16   u16x8 __attribute__((ext_vector_type(8)));
typedef u16   u16x4 __attribute__((ext_vector_type(4)));
typedef __bf16 bf16x8 __attribute__((ext_vector_type(8)));
typedef float f32x4 __attribute__((ext_vector_type(4)));

__device__ __forceinline__ u16 f2bf(float f) {
  u32 u = __builtin_bit_cast(u32, f);
  u += 0x7fffu + ((u >> 16) & 1u);           // round-to-nearest-even
  return (u16)(u >> 16);
}

__device__ __forceinline__ u16 bfc(float f) {  // compiler cvt (packs to cvt_pk)
  return __builtin_bit_cast(u16, (__bf16)f);
}

__device__ __forceinline__ f32x4 mfma16(u16x8 a, u16x8 b, f32x4 c) {
  return __builtin_amdgcn_mfma_f32_16x16x32_bf16(
      __builtin_bit_cast(bf16x8, a), __builtin_bit_cast(bf16x8, b), c, 0, 0, 0);
}

__device__ __forceinline__ void gload16(const u16* g, u16* l) {
  __builtin_amdgcn_global_load_lds((const __attribute__((address_space(1))) void*)g,
                                   (__attribute__((address_space(3))) void*)l,
                                   16, 0, 0);
}

// ---------------- cast f32 -> bf16 with layout fixes ----------------
// ws (u16): [xbm 4M][Wqkv 3M: rows 0..1023 Wq | 1024..2047 Wk | 2048..3071 Wv]
//           [Wob 1M][Qh 4M][Kh 4M][Vt 4M][Aout 4M]
#define XN 4194304u
__global__ __launch_bounds__(256) void cast_all(
    const float* __restrict__ x,  const float* __restrict__ wk,
    const float* __restrict__ wv, const float* __restrict__ wq,
    const float* __restrict__ wo, u16* __restrict__ ws) {
  size_t i = ((size_t)blockIdx.x * 256 + threadIdx.x) * 4;
  const float* src; size_t soff, doff; float sc = 1.0f;
  if (i < XN) {
    int m = (int)(i >> 10), d = (int)(i & 1023);
    int t = m >> 1, b = m & 1;
    src = x; soff = i;
    doff = ((size_t)(b * 2048 + t) << 10) + d;
  } else {
    size_t off = i - XN;
    int wi = (int)(off >> 20);
    off &= 1048575u;
    int u = (int)(off >> 10), c = (int)(off & 1023);
    src = (wi == 0) ? wk : (wi == 1) ? wv : (wi == 2) ? wq : wo;
    soff = off;
    if (wi == 3) {
      doff = XN + 3u * 1048576u + off;                      // Wob linear
    } else {
      int slot = (wi == 2) ? 0 : (wi == 0) ? 1 : 2;         // Q,K,V pack order
      int up = (u & 15) * 64 + (u >> 4);                    // head-outer perm
      doff = XN + (size_t)slot * 1048576u + ((size_t)up << 10) + c;
      if (wi == 2) sc = ATT_SC2;
    }
  }
  float4 v = *reinterpret_cast<const float4*>(src + soff);
  u16x4 o;
  o.s0 = f2bf(v.x * sc); o.s1 = f2bf(v.y * sc); o.s2 = f2bf(v.z * sc); o.s3 = f2bf(v.w * sc);
  *reinterpret_cast<u16x4*>(ws + doff) = o;
}

// ---------------- QKV GEMM: 256x128 tile, BK=64, per-wave 128x64 ----------------
__global__ __launch_bounds__(256, 2) void gemm_qkv(
    const u16* __restrict__ xbm, const u16* __restrict__ Wqkv,
    u16* __restrict__ Qh, u16* __restrict__ Kh, u16* __restrict__ Vt) {
  __shared__ __align__(16) u16 As[256 * 64];   // 32 KB
  __shared__ __align__(16) u16 Bs[128 * 64];   // 16 KB

  const int tid = threadIdx.x;
  const int l  = tid & 63, w = tid >> 6;
  const int lr = l & 15,  lg = l >> 4;
  const int wm = w >> 1,  wn = w & 1;

  const int blk  = blockIdx.x;
  const int wgid = (blk & 7) * 48 + (blk >> 3);   // bijective (384 % 8 == 0)

  const u16 *A, *W;
  int m0, n0, isV;
  if (wgid < 256) {
    const int bx = wgid >> 4, by = wgid & 15;
    A = xbm; W = Wqkv; m0 = by * 256; n0 = bx * 128; isV = 0;
  } else {
    const int v = wgid - 256;
    const int vby = v >> 5, vbx = v & 31;
    A = Wqkv + (2048u << 10); W = xbm; m0 = vby * 256; n0 = vbx * 128; isV = 1;
  }

  f32x4 acc[8][4];
#pragma unroll
  for (int i = 0; i < 8; ++i)
#pragma unroll
    for (int j = 0; j < 4; ++j) acc[i][j] = (f32x4)(0.0f);

  for (int k0 = 0; k0 < KDIM; k0 += 64) {
#pragma unroll
    for (int i = 0; i < 8; ++i) {
      const int base = i * 256 + w * 64;
      const int p = base + l;
      const int r = p >> 3, c = p & 7;
      gload16(A + (size_t)(m0 + r) * KDIM + k0 + ((c ^ (r & 7)) << 3),
              As + (size_t)base * 8);
    }
#pragma unroll
    for (int i = 0; i < 4; ++i) {
      const int base = i * 256 + w * 64;
      const int p = base + l;
      const int r = p >> 3, c = p & 7;
      gload16(W + (size_t)(n0 + r) * KDIM + k0 + ((c ^ (r & 7)) << 3),
              Bs + (size_t)base * 8);
    }
    __syncthreads();

#pragma unroll
    for (int ks = 0; ks < 2; ++ks) {
      const int cr = ks * 4 + lg;
      u16x8 bf_[4];
#pragma unroll
      for (int ni = 0; ni < 4; ++ni) {
        const int rr = wn * 64 + ni * 16 + lr;
        bf_[ni] = *reinterpret_cast<const u16x8*>(Bs + rr * 64 + ((cr ^ (rr & 7)) << 3));
      }
      __builtin_amdgcn_s_setprio(1);
#pragma unroll
      for (int mi = 0; mi < 8; ++mi) {
        const int rr = wm * 128 + mi * 16 + lr;
        const u16x8 af = *reinterpret_cast<const u16x8*>(
            As + rr * 64 + ((cr ^ (rr & 7)) << 3));
#pragma unroll
        for (int ni = 0; ni < 4; ++ni)
          acc[mi][ni] = mfma16(af, bf_[ni], acc[mi][ni]);
      }
      __builtin_amdgcn_s_setprio(0);
    }
    __syncthreads();
  }

#pragma unroll
  for (int mi = 0; mi < 8; ++mi)
#pragma unroll
    for (int ni = 0; ni < 4; ++ni)
#pragma unroll
      for (int r = 0; r < 4; ++r) {
        const int row = m0 + wm * 128 + mi * 16 + lg * 4 + r;
        const int col = n0 + wn * 64 + ni * 16 + lr;
        const u16 v = bfc(acc[mi][ni][r]);
        if (!isV) {
          const int bb = row >> 11, t = row & 2047;
          const int c = col & 1023, hh = c >> 6, dp = c & 63;
          u16* d = (col < 1024) ? Qh : Kh;
          d[(((size_t)(bb * NHEAD + hh) << 11) + t) * 64 + dp] = v;
        } else {
          const int hh = row >> 6, dp = row & 63;
          const int bb = col >> 11, t = col & 2047;
          Vt[((((size_t)(bb * NHEAD + hh)) * 64 + dp) << 11) + t] = v;
        }
      }
}

// ---------------- O projection: 128x64 tile, 512 blocks (grid-rich) ----------------
__global__ __launch_bounds__(256) void gemm_o(
    const u16* __restrict__ A, const u16* __restrict__ W, float* __restrict__ out) {
  __shared__ __align__(16) u16 As[128 * 64];   // 16 KB
  __shared__ __align__(16) u16 Bs[64 * 64];    // 8 KB

  const int tid = threadIdx.x;
  const int l  = tid & 63, w = tid >> 6;
  const int lr = l & 15,  lg = l >> 4;
  const int wm = w >> 1,  wn = w & 1;

  const int blk  = blockIdx.x;
  const int wgid = (blk & 7) * 64 + (blk >> 3);   // bijective (512 % 8 == 0)
  const int bx = wgid >> 5, by = wgid & 31;       // same-bx grouped per XCD
  const int m0 = by * 128;
  const int n0 = bx * 64;

  f32x4 acc[4][2];
#pragma unroll
  for (int i = 0; i < 4; ++i)
#pragma unroll
    for (int j = 0; j < 2; ++j) acc[i][j] = (f32x4)(0.0f);

  for (int k0 = 0; k0 < KDIM; k0 += 64) {
#pragma unroll
    for (int i = 0; i < 4; ++i) {                 // A: 1024 chunks
      const int base = i * 256 + w * 64;
      const int p = base + l;
      const int r = p >> 3, c = p & 7;
      gload16(A + (size_t)(m0 + r) * KDIM + k0 + ((c ^ (r & 7)) << 3),
              As + (size_t)base * 8);
    }
#pragma unroll
    for (int i = 0; i < 2; ++i) {                 // B: 512 chunks
      const int base = i * 256 + w * 64;
      const int p = base + l;
      const int r = p >> 3, c = p & 7;
      gload16(W + (size_t)(n0 + r) * KDIM + k0 + ((c ^ (r & 7)) << 3),
              Bs + (size_t)base * 8);
    }
    __syncthreads();

#pragma unroll
    for (int ks = 0; ks < 2; ++ks) {
      const int cr = ks * 4 + lg;
      u16x8 bf_[2];
#pragma unroll
      for (int ni = 0; ni < 2; ++ni) {
        const int rr = wn * 32 + ni * 16 + lr;
        bf_[ni] = *reinterpret_cast<const u16x8*>(Bs + rr * 64 + ((cr ^ (rr & 7)) << 3));
      }
      __builtin_amdgcn_s_setprio(1);
#pragma unroll
      for (int mi = 0; mi < 4; ++mi) {
        const int rr = wm * 64 + mi * 16 + lr;
        const u16x8 af = *reinterpret_cast<const u16x8*>(
            As + rr * 64 + ((cr ^ (rr & 7)) << 3));
#pragma unroll
        for (int ni = 0; ni < 2; ++ni)
          acc[mi][ni] = mfma16(af, bf_[ni], acc[mi][ni]);
      }
      __builtin_amdgcn_s_setprio(0);
    }
    __syncthreads();
  }

#pragma unroll
  for (int mi = 0; mi < 4; ++mi)
#pragma unroll
    for (int ni = 0; ni < 2; ++ni)
#pragma unroll
      for (int r = 0; r < 4; ++r) {
        const int row = m0 + wm * 64 + mi * 16 + lg * 4 + r;  // b*2048+t
        const int col = n0 + wn * 32 + ni * 16 + lr;
        const int t = row & 2047, bb = row >> 11;
        out[((size_t)(t * 2 + bb) << 10) + col] = acc[mi][ni][r];
      }
}

// ---------------- causal flash attention v17: 8-wave kv-64, conflict-free Pw ----------------
// 8 waves x 512 threads (wq{0..3} x wk{0,1}), kv-64, counted-vmcnt raw
// barriers, fixed-shift softmax. Pw rows padded to 40 u16 (80 B), no XOR:
// pa b128 read and pk b64 write are 2-way max (free). LDS 42 KB -> 2 blk/CU.
__global__ __launch_bounds__(512, 2) void attn_fwd(
    const u16* __restrict__ Qh, const u16* __restrict__ Kh,
    const u16* __restrict__ Vt, u16* __restrict__ Aout) {
  // u16 carve: Ks[2][4096]=0..8191 | Vs[2][4096]=8192..16383 | Pw 8x640=16384..21503
  __shared__ __align__(16) u16 smem[21504];

  const int tid = threadIdx.x;
  const int l = tid & 63, w = tid >> 6;           // w 0..7
  const int lr = l & 15, lg = l >> 4;
  const int wk = w & 1, wq = w >> 1;              // wq 0..3
  const int blk = blockIdx.x;
  const int bxx = (blk >> 3) & 15;
  const int bh  = ((blk >> 7) << 3) + (blk & 7);  // XCD-grouped heads
  const int b = bh >> 4, h = bh & 15;

  const u16* kg = Kh + ((size_t)bh << 17);    // [t][64]
  const u16* vg = Vt + ((size_t)bh << 17);    // [64][2048]
  u16* Pw = smem + 16384 + w * 640;           // per-wave P tile [16 q][40 pad]

  float* redO = reinterpret_cast<float*>(smem);            // 4 x [16 q][68] = 17408 B
  float* redS = reinterpret_cast<float*>(smem + 16384);    // 64 floats over dead Pw

  const u16x8 ones = {0x3F80,0x3F80,0x3F80,0x3F80,0x3F80,0x3F80,0x3F80,0x3F80};

  auto stage = [&](int buf, int kv0) {        // K 512 + V 512 chunks; 1 each/thread
    u16* kb = smem + buf * 4096;
    u16* vb = smem + 8192 + buf * 4096;
    const int p = w * 64 + l;                 // chunk id 0..511
    const int r = p >> 3, c = p & 7;          // row 0..63, chunk 0..7
    const int cs = ((c ^ (r & 7)) << 3);
    gload16(kg + (size_t)(kv0 + r) * 64 + cs, kb + (size_t)(w * 64) * 8);
    gload16(vg + ((size_t)r << 11) + kv0 + cs, vb + (size_t)(w * 64) * 8);
  };

  for (int ph = 0; ph < 2; ++ph) {
    const int qb = ph ? bxx : 31 - bxx;
    const int qbw = qb * 64 + wq * 16;        // wave's 16-q window start
    const int qrow = qbw + lr;

    const u16* qptr = Qh + (((size_t)bh << 11) + qrow) * 64 + lg * 8;
    const u16x8 qf0 = *reinterpret_cast<const u16x8*>(qptr);
    const u16x8 qf1 = *reinterpret_cast<const u16x8*>(qptr + 32);

    f32x4 oacc[4];
#pragma unroll
    for (int i = 0; i < 4; ++i) oacc[i] = (f32x4)(0.0f);
    f32x4 sum4 = (f32x4)(0.0f);

    const int nt = qb + 1;                    // kv-64 tiles
    stage(0, 0);
    __syncthreads();                           // prologue: full drain ok

    int cur = 0;
    for (int t = 0; t < nt; ++t) {
      const int kv0 = t * 64;
      const bool pf = (t + 1 < nt);
      if (pf) {
        stage(cur ^ 1, kv0 + 64);              // issue 2 loads, keep in flight
        asm volatile("s_waitcnt vmcnt(2)" ::: "memory");   // tile t ready
      } else {
        asm volatile("s_waitcnt vmcnt(0)" ::: "memory");
      }
      __builtin_amdgcn_sched_barrier(0);
      __builtin_amdgcn_s_barrier();            // all waves: tile t ready

      const int kvw = kv0 + wk * 32;          // wave's 32-kv window start
      if (kvw <= qbw + 15) {                  // wave has live work
        const u16* kb = smem + cur * 4096;
        const u16* vb = smem + 8192 + cur * 4096;

        u16x8 kf[2][2];
#pragma unroll
        for (int tt = 0; tt < 2; ++tt) {
          const int row = wk * 32 + tt * 16 + lr;
          kf[tt][0] = *reinterpret_cast<const u16x8*>(
              kb + row * 64 + ((lg ^ (row & 7)) << 3));
          kf[tt][1] = *reinterpret_cast<const u16x8*>(
              kb + row * 64 + (((4 + lg) ^ (row & 7)) << 3));
        }
        u16x8 vf[4];
#pragma unroll
        for (int ni = 0; ni < 4; ++ni) {
          const int dr = ni * 16 + lr;
          const int ck = wk * 4 + lg;
          vf[ni] = *reinterpret_cast<const u16x8*>(
              vb + dr * 64 + ((ck ^ (dr & 7)) << 3));
        }

        const bool diag = (kvw + 31 > qbw);

        // ---- QK^T -> mask -> exp2(S-8) -> pack -> Pw (per tt)
        __builtin_amdgcn_s_setprio(1);
#pragma unroll
        for (int tt = 0; tt < 2; ++tt) {
          f32x4 sacc = (f32x4)(0.0f);
          sacc = mfma16(kf[tt][0], qf0, sacc);
          sacc = mfma16(kf[tt][1], qf1, sacc);
          u16x4 pk;
#pragma unroll
          for (int r = 0; r < 4; ++r) {
            const int kv = kvw + tt * 16 + lg * 4 + r;
            const float s = (diag && kv > qrow) ? -1e30f : sacc[r];
            pk[r] = bfc(__builtin_amdgcn_exp2f(s - 8.0f));
          }
          // row lr (stride 40 u16), col kv = tt*16 + lg*4 : conflict-free pad
          *reinterpret_cast<u16x4*>(&Pw[lr * 40 + tt * 16 + lg * 4]) = pk;
        }

        // ---- PV + MFMA row-sum over the 32-kv window (K=32, one A-frag)
        {
          const u16x8 pa = *reinterpret_cast<const u16x8*>(&Pw[lr * 40 + lg * 8]);
          sum4 = mfma16(pa, ones, sum4);       // row-sum in O's C-layout
#pragma unroll
          for (int ni = 0; ni < 4; ++ni)
            oacc[ni] = mfma16(pa, vf[ni], oacc[ni]);
        }
        __builtin_amdgcn_s_setprio(0);
      }

      asm volatile("s_waitcnt lgkmcnt(0)" ::: "memory");   // done reading cur
      __builtin_amdgcn_sched_barrier(0);
      __builtin_amdgcn_s_barrier();            // cur may be overwritten
      cur ^= 1;
    }

    // ---- wk-pair combine: wk=1 publishes partials, wk=0 adds + stores.
    if (wk) {
      float* po = redO + wq * 1088;           // [16 q][stride 68]
#pragma unroll
      for (int ni = 0; ni < 4; ++ni)
#pragma unroll
        for (int r = 0; r < 4; ++r)
          po[(lg * 4 + r) * 68 + ni * 16 + lr] = oacc[ni][r];
      if (lr == 0) {
#pragma unroll
        for (int r = 0; r < 4; ++r)
          redS[wq * 16 + lg * 4 + r] = sum4[r];
      }
    }
    __syncthreads();

    if (!wk) {
      const float* po = redO + wq * 1088;
      f32x4 ss = sum4;
#pragma unroll
      for (int r = 0; r < 4; ++r)
        ss[r] += redS[wq * 16 + lg * 4 + r];
#pragma unroll
      for (int r = 0; r < 4; ++r) {
        const float inv = 1.0f / ss[r];
        const int q = qbw + lg * 4 + r;
        const size_t rowbase = (((size_t)(b * 2048 + q)) << 10) + h * DHEAD;
#pragma unroll
        for (int ni = 0; ni < 4; ++ni)
          Aout[rowbase + ni * 16 + lr] = bfc(
              (oacc[ni][r] + po[(lg * 4 + r) * 68 + ni * 16 + lr]) * inv);
      }
    }
    __syncthreads();   // redO/redS (aliased on Ks/Vs/Pw) free before next stage
  }
}

// ---------------- launch ----------------
extern "C" void kernel_launch(void* const* d_in, const int* in_sizes, int n_in,
                              void* d_out, int out_size, void* d_ws, size_t ws_size,
                              hipStream_t stream) {
  const float* x  = (const float*)d_in[0];
  const float* Wk = (const float*)d_in[1];
  const float* Wv = (const float*)d_in[2];
  const float* Wq = (const float*)d_in[3];
  const float* Wo = (const float*)d_in[4];
  // d_in[5] = mask (causal, known structurally)

  u16* ws   = (u16*)d_ws;
  u16* xbm  = ws;                      // 4M  [b*2048+t][d]
  u16* Wqkv = xbm + 4194304;           // 3M  [Wq|Wk|Wv], head-perm rows
  u16* Wob  = Wqkv + 3145728;          // 1M
  u16* Qh   = Wob + 1048576;           // 4M  [bh][t][64]
  u16* Kh   = Qh  + 4194304;           // 4M  [bh][t][64]
  u16* Vt   = Kh  + 4194304;           // 4M  [bh][64][t]
  u16* Aout = Vt  + 4194304;           // 4M  [b*2048+t][h*64+dp]

  cast_all<<<8192, 256, 0, stream>>>(x, Wk, Wv, Wq, Wo, ws);

  gemm_qkv<<<384, 256, 0, stream>>>(xbm, Wqkv, Qh, Kh, Vt);

  attn_fwd<<<512, 512, 0, stream>>>(Qh, Kh, Vt, Aout);

  gemm_o<<<512, 256, 0, stream>>>(Aout, Wob, (float*)d_out);
}

// Round 22
// 99.229 us; speedup vs baseline: 1.1983x; 1.0555x over previous
//
#include <hip/hip_runtime.h>

// ---------------- problem constants ----------------
#define T_LEN   2048
#define BATCH   2
#define DMODEL  1024
#define NHEAD   16
#define DHEAD   64
#define MROWS   4096          // T*B
#define KDIM    1024
#define NDIM    1024
#define ATT_SC2 (0.125f * 1.44269504088896f)   // SCALE * log2(e), folded into Wq

typedef unsigned short u16;
typedef unsigned int   u32;
typedef u16   u16x8 __attribute__((ext_vector_type(8)));
typedef u16   u16x4 __attribute__((ext_vector_type(4)));
typedef __bf16 bf16x8 __attribute__((ext_vector_type(8)));
typedef float f32x4 __attribute__((ext_vector_type(4)));

__device__ __forceinline__ u16 f2bf(float f) {
  u32 u = __builtin_bit_cast(u32, f);
  u += 0x7fffu + ((u >> 16) & 1u);           // round-to-nearest-even
  return (u16)(u >> 16);
}

__device__ __forceinline__ u16 bfc(float f) {  // compiler cvt (packs to cvt_pk)
  return __builtin_bit_cast(u16, (__bf16)f);
}

__device__ __forceinline__ f32x4 mfma16(u16x8 a, u16x8 b, f32x4 c) {
  return __builtin_amdgcn_mfma_f32_16x16x32_bf16(
      __builtin_bit_cast(bf16x8, a), __builtin_bit_cast(bf16x8, b), c, 0, 0, 0);
}

__device__ __forceinline__ void gload16(const u16* g, u16* l) {
  __builtin_amdgcn_global_load_lds((const __attribute__((address_space(1))) void*)g,
                                   (__attribute__((address_space(3))) void*)l,
                                   16, 0, 0);
}

// ---------------- cast f32 -> bf16 with layout fixes ----------------
// ws (u16): [xbm 4M][Wqkv 3M: rows 0..1023 Wq | 1024..2047 Wk | 2048..3071 Wv]
//           [Wob 1M][Qh 4M][Kh 4M][Vt 4M][Aout 4M]
#define XN 4194304u
__global__ __launch_bounds__(256) void cast_all(
    const float* __restrict__ x,  const float* __restrict__ wk,
    const float* __restrict__ wv, const float* __restrict__ wq,
    const float* __restrict__ wo, u16* __restrict__ ws) {
  size_t i = ((size_t)blockIdx.x * 256 + threadIdx.x) * 4;
  const float* src; size_t soff, doff; float sc = 1.0f;
  if (i < XN) {
    int m = (int)(i >> 10), d = (int)(i & 1023);
    int t = m >> 1, b = m & 1;
    src = x; soff = i;
    doff = ((size_t)(b * 2048 + t) << 10) + d;
  } else {
    size_t off = i - XN;
    int wi = (int)(off >> 20);
    off &= 1048575u;
    int u = (int)(off >> 10), c = (int)(off & 1023);
    src = (wi == 0) ? wk : (wi == 1) ? wv : (wi == 2) ? wq : wo;
    soff = off;
    if (wi == 3) {
      doff = XN + 3u * 1048576u + off;                      // Wob linear
    } else {
      int slot = (wi == 2) ? 0 : (wi == 0) ? 1 : 2;         // Q,K,V pack order
      int up = (u & 15) * 64 + (u >> 4);                    // head-outer perm
      doff = XN + (size_t)slot * 1048576u + ((size_t)up << 10) + c;
      if (wi == 2) sc = ATT_SC2;
    }
  }
  float4 v = *reinterpret_cast<const float4*>(src + soff);
  u16x4 o;
  o.s0 = f2bf(v.x * sc); o.s1 = f2bf(v.y * sc); o.s2 = f2bf(v.z * sc); o.s3 = f2bf(v.w * sc);
  *reinterpret_cast<u16x4*>(ws + doff) = o;
}

// ---------------- QKV GEMM v2: balanced 512-block grid ----------------
// Per XCD (xcd = blk&7), j = blk>>3 in 0..63:
//   j <  32 : QK tile 256x128 (A = xbm, W = Wq|Wk)       -- 256 blocks total
//   j >= 32 : V  tile 128x128 swapped (A = Wv, W = xbm)  -- 256 blocks total
// Dispatch order => each CU gets 1 QK + 1 V (uniform 1.5 cost units).
__global__ __launch_bounds__(256, 2) void gemm_qkv(
    const u16* __restrict__ xbm, const u16* __restrict__ Wqkv,
    u16* __restrict__ Qh, u16* __restrict__ Kh, u16* __restrict__ Vt) {
  __shared__ __align__(16) u16 As[256 * 64];   // 32 KB
  __shared__ __align__(16) u16 Bs[128 * 64];   // 16 KB

  const int tid = threadIdx.x;
  const int l  = tid & 63, w = tid >> 6;
  const int lr = l & 15,  lg = l >> 4;
  const int wm = w >> 1,  wn = w & 1;

  const int blk = blockIdx.x;
  const int xcd = blk & 7, j = blk >> 3;
  const int isV = (j >= 32);

  if (!isV) {
    // ---------- QK: 256x128, per-wave 128x64, acc[8][4] ----------
    const int qidx = xcd * 32 + j;              // 0..255
    const int bx = qidx >> 4, by = qidx & 15;   // same-bx grouped per XCD
    const int m0 = by * 256, n0 = bx * 128;

    f32x4 acc[8][4];
#pragma unroll
    for (int i = 0; i < 8; ++i)
#pragma unroll
      for (int jj = 0; jj < 4; ++jj) acc[i][jj] = (f32x4)(0.0f);

    for (int k0 = 0; k0 < KDIM; k0 += 64) {
#pragma unroll
      for (int i = 0; i < 8; ++i) {
        const int base = i * 256 + w * 64;
        const int p = base + l;
        const int r = p >> 3, c = p & 7;
        gload16(xbm + (size_t)(m0 + r) * KDIM + k0 + ((c ^ (r & 7)) << 3),
                As + (size_t)base * 8);
      }
#pragma unroll
      for (int i = 0; i < 4; ++i) {
        const int base = i * 256 + w * 64;
        const int p = base + l;
        const int r = p >> 3, c = p & 7;
        gload16(Wqkv + (size_t)(n0 + r) * KDIM + k0 + ((c ^ (r & 7)) << 3),
                Bs + (size_t)base * 8);
      }
      __syncthreads();

#pragma unroll
      for (int ks = 0; ks < 2; ++ks) {
        const int cr = ks * 4 + lg;
        u16x8 bf_[4];
#pragma unroll
        for (int ni = 0; ni < 4; ++ni) {
          const int rr = wn * 64 + ni * 16 + lr;
          bf_[ni] = *reinterpret_cast<const u16x8*>(Bs + rr * 64 + ((cr ^ (rr & 7)) << 3));
        }
        __builtin_amdgcn_s_setprio(1);
#pragma unroll
        for (int mi = 0; mi < 8; ++mi) {
          const int rr = wm * 128 + mi * 16 + lr;
          const u16x8 af = *reinterpret_cast<const u16x8*>(
              As + rr * 64 + ((cr ^ (rr & 7)) << 3));
#pragma unroll
          for (int ni = 0; ni < 4; ++ni)
            acc[mi][ni] = mfma16(af, bf_[ni], acc[mi][ni]);
        }
        __builtin_amdgcn_s_setprio(0);
      }
      __syncthreads();
    }

#pragma unroll
    for (int mi = 0; mi < 8; ++mi)
#pragma unroll
      for (int ni = 0; ni < 4; ++ni)
#pragma unroll
        for (int r = 0; r < 4; ++r) {
          const int row = m0 + wm * 128 + mi * 16 + lg * 4 + r;  // b*2048+t
          const int col = n0 + wn * 64 + ni * 16 + lr;           // 0..2047
          const u16 v = bfc(acc[mi][ni][r]);
          const int bb = row >> 11, t = row & 2047;
          const int c = col & 1023, hh = c >> 6, dp = c & 63;
          u16* d = (col < 1024) ? Qh : Kh;
          d[(((size_t)(bb * NHEAD + hh) << 11) + t) * 64 + dp] = v;
        }
  } else {
    // ---------- V swapped: 128x128, per-wave 64x64, acc[4][4] ----------
    const int vidx = xcd * 32 + (j - 32);       // 0..255
    const int vby = vidx >> 5, vbx = vidx & 31; // m 0..7, n 0..31
    const int m0 = vby * 128, n0 = vbx * 128;
    const u16* Wv = Wqkv + (2048u << 10);

    f32x4 acc[4][4];
#pragma unroll
    for (int i = 0; i < 4; ++i)
#pragma unroll
      for (int jj = 0; jj < 4; ++jj) acc[i][jj] = (f32x4)(0.0f);

    for (int k0 = 0; k0 < KDIM; k0 += 64) {
#pragma unroll
      for (int i = 0; i < 4; ++i) {             // A: Wv 128x64
        const int base = i * 256 + w * 64;
        const int p = base + l;
        const int r = p >> 3, c = p & 7;
        gload16(Wv + (size_t)(m0 + r) * KDIM + k0 + ((c ^ (r & 7)) << 3),
                As + (size_t)base * 8);
      }
#pragma unroll
      for (int i = 0; i < 4; ++i) {             // B: xbm 128x64
        const int base = i * 256 + w * 64;
        const int p = base + l;
        const int r = p >> 3, c = p & 7;
        gload16(xbm + (size_t)(n0 + r) * KDIM + k0 + ((c ^ (r & 7)) << 3),
                Bs + (size_t)base * 8);
      }
      __syncthreads();

#pragma unroll
      for (int ks = 0; ks < 2; ++ks) {
        const int cr = ks * 4 + lg;
        u16x8 bf_[4];
#pragma unroll
        for (int ni = 0; ni < 4; ++ni) {
          const int rr = wn * 64 + ni * 16 + lr;
          bf_[ni] = *reinterpret_cast<const u16x8*>(Bs + rr * 64 + ((cr ^ (rr & 7)) << 3));
        }
        __builtin_amdgcn_s_setprio(1);
#pragma unroll
        for (int mi = 0; mi < 4; ++mi) {
          const int rr = wm * 64 + mi * 16 + lr;
          const u16x8 af = *reinterpret_cast<const u16x8*>(
              As + rr * 64 + ((cr ^ (rr & 7)) << 3));
#pragma unroll
          for (int ni = 0; ni < 4; ++ni)
            acc[mi][ni] = mfma16(af, bf_[ni], acc[mi][ni]);
        }
        __builtin_amdgcn_s_setprio(0);
      }
      __syncthreads();
    }

#pragma unroll
    for (int mi = 0; mi < 4; ++mi)
#pragma unroll
      for (int ni = 0; ni < 4; ++ni)
#pragma unroll
        for (int r = 0; r < 4; ++r) {
          const int row = m0 + wm * 64 + mi * 16 + lg * 4 + r;   // h*64+dp
          const int col = n0 + wn * 64 + ni * 16 + lr;           // b*2048+t
          const int hh = row >> 6, dp = row & 63;
          const int bb = col >> 11, t = col & 2047;
          Vt[((((size_t)(bb * NHEAD + hh)) * 64 + dp) << 11) + t] = bfc(acc[mi][ni][r]);
        }
  }
}

// ---------------- O projection: 128x64 tile, 512 blocks (grid-rich) ----------------
__global__ __launch_bounds__(256) void gemm_o(
    const u16* __restrict__ A, const u16* __restrict__ W, float* __restrict__ out) {
  __shared__ __align__(16) u16 As[128 * 64];   // 16 KB
  __shared__ __align__(16) u16 Bs[64 * 64];    // 8 KB

  const int tid = threadIdx.x;
  const int l  = tid & 63, w = tid >> 6;
  const int lr = l & 15,  lg = l >> 4;
  const int wm = w >> 1,  wn = w & 1;

  const int blk  = blockIdx.x;
  const int wgid = (blk & 7) * 64 + (blk >> 3);   // bijective (512 % 8 == 0)
  const int bx = wgid >> 5, by = wgid & 31;       // same-bx grouped per XCD
  const int m0 = by * 128;
  const int n0 = bx * 64;

  f32x4 acc[4][2];
#pragma unroll
  for (int i = 0; i < 4; ++i)
#pragma unroll
    for (int j = 0; j < 2; ++j) acc[i][j] = (f32x4)(0.0f);

  for (int k0 = 0; k0 < KDIM; k0 += 64) {
#pragma unroll
    for (int i = 0; i < 4; ++i) {                 // A: 1024 chunks
      const int base = i * 256 + w * 64;
      const int p = base + l;
      const int r = p >> 3, c = p & 7;
      gload16(A + (size_t)(m0 + r) * KDIM + k0 + ((c ^ (r & 7)) << 3),
              As + (size_t)base * 8);
    }
#pragma unroll
    for (int i = 0; i < 2; ++i) {                 // B: 512 chunks
      const int base = i * 256 + w * 64;
      const int p = base + l;
      const int r = p >> 3, c = p & 7;
      gload16(W + (size_t)(n0 + r) * KDIM + k0 + ((c ^ (r & 7)) << 3),
              Bs + (size_t)base * 8);
    }
    __syncthreads();

#pragma unroll
    for (int ks = 0; ks < 2; ++ks) {
      const int cr = ks * 4 + lg;
      u16x8 bf_[2];
#pragma unroll
      for (int ni = 0; ni < 2; ++ni) {
        const int rr = wn * 32 + ni * 16 + lr;
        bf_[ni] = *reinterpret_cast<const u16x8*>(Bs + rr * 64 + ((cr ^ (rr & 7)) << 3));
      }
      __builtin_amdgcn_s_setprio(1);
#pragma unroll
      for (int mi = 0; mi < 4; ++mi) {
        const int rr = wm * 64 + mi * 16 + lr;
        const u16x8 af = *reinterpret_cast<const u16x8*>(
            As + rr * 64 + ((cr ^ (rr & 7)) << 3));
#pragma unroll
        for (int ni = 0; ni < 2; ++ni)
          acc[mi][ni] = mfma16(af, bf_[ni], acc[mi][ni]);
      }
      __builtin_amdgcn_s_setprio(0);
    }
    __syncthreads();
  }

#pragma unroll
  for (int mi = 0; mi < 4; ++mi)
#pragma unroll
    for (int ni = 0; ni < 2; ++ni)
#pragma unroll
      for (int r = 0; r < 4; ++r) {
        const int row = m0 + wm * 64 + mi * 16 + lg * 4 + r;  // b*2048+t
        const int col = n0 + wn * 32 + ni * 16 + lr;
        const int t = row & 2047, bb = row >> 11;
        out[((size_t)(t * 2 + bb) << 10) + col] = acc[mi][ni][r];
      }
}

// ---------------- causal flash attention v17 (r19/r21 winner, verbatim) ----------------
__global__ __launch_bounds__(512, 2) void attn_fwd(
    const u16* __restrict__ Qh, const u16* __restrict__ Kh,
    const u16* __restrict__ Vt, u16* __restrict__ Aout) {
  // u16 carve: Ks[2][4096]=0..8191 | Vs[2][4096]=8192..16383 | Pw 8x640=16384..21503
  __shared__ __align__(16) u16 smem[21504];

  const int tid = threadIdx.x;
  const int l = tid & 63, w = tid >> 6;           // w 0..7
  const int lr = l & 15, lg = l >> 4;
  const int wk = w & 1, wq = w >> 1;              // wq 0..3
  const int blk = blockIdx.x;
  const int bxx = (blk >> 3) & 15;
  const int bh  = ((blk >> 7) << 3) + (blk & 7);  // XCD-grouped heads
  const int b = bh >> 4, h = bh & 15;

  const u16* kg = Kh + ((size_t)bh << 17);    // [t][64]
  const u16* vg = Vt + ((size_t)bh << 17);    // [64][2048]
  u16* Pw = smem + 16384 + w * 640;           // per-wave P tile [16 q][40 pad]

  float* redO = reinterpret_cast<float*>(smem);            // 4 x [16 q][68] = 17408 B
  float* redS = reinterpret_cast<float*>(smem + 16384);    // 64 floats over dead Pw

  const u16x8 ones = {0x3F80,0x3F80,0x3F80,0x3F80,0x3F80,0x3F80,0x3F80,0x3F80};

  auto stage = [&](int buf, int kv0) {        // K 512 + V 512 chunks; 1 each/thread
    u16* kb = smem + buf * 4096;
    u16* vb = smem + 8192 + buf * 4096;
    const int p = w * 64 + l;                 // chunk id 0..511
    const int r = p >> 3, c = p & 7;          // row 0..63, chunk 0..7
    const int cs = ((c ^ (r & 7)) << 3);
    gload16(kg + (size_t)(kv0 + r) * 64 + cs, kb + (size_t)(w * 64) * 8);
    gload16(vg + ((size_t)r << 11) + kv0 + cs, vb + (size_t)(w * 64) * 8);
  };

  for (int ph = 0; ph < 2; ++ph) {
    const int qb = ph ? bxx : 31 - bxx;
    const int qbw = qb * 64 + wq * 16;        // wave's 16-q window start
    const int qrow = qbw + lr;

    const u16* qptr = Qh + (((size_t)bh << 11) + qrow) * 64 + lg * 8;
    const u16x8 qf0 = *reinterpret_cast<const u16x8*>(qptr);
    const u16x8 qf1 = *reinterpret_cast<const u16x8*>(qptr + 32);

    f32x4 oacc[4];
#pragma unroll
    for (int i = 0; i < 4; ++i) oacc[i] = (f32x4)(0.0f);
    f32x4 sum4 = (f32x4)(0.0f);

    const int nt = qb + 1;                    // kv-64 tiles
    stage(0, 0);
    __syncthreads();                           // prologue: full drain ok

    int cur = 0;
    for (int t = 0; t < nt; ++t) {
      const int kv0 = t * 64;
      const bool pf = (t + 1 < nt);
      if (pf) {
        stage(cur ^ 1, kv0 + 64);              // issue 2 loads, keep in flight
        asm volatile("s_waitcnt vmcnt(2)" ::: "memory");   // tile t ready
      } else {
        asm volatile("s_waitcnt vmcnt(0)" ::: "memory");
      }
      __builtin_amdgcn_sched_barrier(0);
      __builtin_amdgcn_s_barrier();            // all waves: tile t ready

      const int kvw = kv0 + wk * 32;          // wave's 32-kv window start
      if (kvw <= qbw + 15) {                  // wave has live work
        const u16* kb = smem + cur * 4096;
        const u16* vb = smem + 8192 + cur * 4096;

        u16x8 kf[2][2];
#pragma unroll
        for (int tt = 0; tt < 2; ++tt) {
          const int row = wk * 32 + tt * 16 + lr;
          kf[tt][0] = *reinterpret_cast<const u16x8*>(
              kb + row * 64 + ((lg ^ (row & 7)) << 3));
          kf[tt][1] = *reinterpret_cast<const u16x8*>(
              kb + row * 64 + (((4 + lg) ^ (row & 7)) << 3));
        }
        u16x8 vf[4];
#pragma unroll
        for (int ni = 0; ni < 4; ++ni) {
          const int dr = ni * 16 + lr;
          const int ck = wk * 4 + lg;
          vf[ni] = *reinterpret_cast<const u16x8*>(
              vb + dr * 64 + ((ck ^ (dr & 7)) << 3));
        }

        const bool diag = (kvw + 31 > qbw);

        // ---- QK^T -> mask -> exp2(S-8) -> pack -> Pw (per tt)
        __builtin_amdgcn_s_setprio(1);
#pragma unroll
        for (int tt = 0; tt < 2; ++tt) {
          f32x4 sacc = (f32x4)(0.0f);
          sacc = mfma16(kf[tt][0], qf0, sacc);
          sacc = mfma16(kf[tt][1], qf1, sacc);
          u16x4 pk;
#pragma unroll
          for (int r = 0; r < 4; ++r) {
            const int kv = kvw + tt * 16 + lg * 4 + r;
            const float s = (diag && kv > qrow) ? -1e30f : sacc[r];
            pk[r] = bfc(__builtin_amdgcn_exp2f(s - 8.0f));
          }
          // row lr (stride 40 u16), col kv = tt*16 + lg*4 : conflict-free pad
          *reinterpret_cast<u16x4*>(&Pw[lr * 40 + tt * 16 + lg * 4]) = pk;
        }

        // ---- PV + MFMA row-sum over the 32-kv window (K=32, one A-frag)
        {
          const u16x8 pa = *reinterpret_cast<const u16x8*>(&Pw[lr * 40 + lg * 8]);
          sum4 = mfma16(pa, ones, sum4);       // row-sum in O's C-layout
#pragma unroll
          for (int ni = 0; ni < 4; ++ni)
            oacc[ni] = mfma16(pa, vf[ni], oacc[ni]);
        }
        __builtin_amdgcn_s_setprio(0);
      }

      asm volatile("s_waitcnt lgkmcnt(0)" ::: "memory");   // done reading cur
      __builtin_amdgcn_sched_barrier(0);
      __builtin_amdgcn_s_barrier();            // cur may be overwritten
      cur ^= 1;
    }

    // ---- wk-pair combine: wk=1 publishes partials, wk=0 adds + stores.
    if (wk) {
      float* po = redO + wq * 1088;           // [16 q][stride 68]
#pragma unroll
      for (int ni = 0; ni < 4; ++ni)
#pragma unroll
        for (int r = 0; r < 4; ++r)
          po[(lg * 4 + r) * 68 + ni * 16 + lr] = oacc[ni][r];
      if (lr == 0) {
#pragma unroll
        for (int r = 0; r < 4; ++r)
          redS[wq * 16 + lg * 4 + r] = sum4[r];
      }
    }
    __syncthreads();

    if (!wk) {
      const float* po = redO + wq * 1088;
      f32x4 ss = sum4;
#pragma unroll
      for (int r = 0; r < 4; ++r)
        ss[r] += redS[wq * 16 + lg * 4 + r];
#pragma unroll
      for (int r = 0; r < 4; ++r) {
        const float inv = 1.0f / ss[r];
        const int q = qbw + lg * 4 + r;
        const size_t rowbase = (((size_t)(b * 2048 + q)) << 10) + h * DHEAD;
#pragma unroll
        for (int ni = 0; ni < 4; ++ni)
          Aout[rowbase + ni * 16 + lr] = bfc(
              (oacc[ni][r] + po[(lg * 4 + r) * 68 + ni * 16 + lr]) * inv);
      }
    }
    __syncthreads();   // redO/redS (aliased on Ks/Vs/Pw) free before next stage
  }
}

// ---------------- launch ----------------
extern "C" void kernel_launch(void* const* d_in, const int* in_sizes, int n_in,
                              void* d_out, int out_size, void* d_ws, size_t ws_size,
                              hipStream_t stream) {
  const float* x  = (const float*)d_in[0];
  const float* Wk = (const float*)d_in[1];
  const float* Wv = (const float*)d_in[2];
  const float* Wq = (const float*)d_in[3];
  const float* Wo = (const float*)d_in[4];
  // d_in[5] = mask (causal, known structurally)

  u16* ws   = (u16*)d_ws;
  u16* xbm  = ws;                      // 4M  [b*2048+t][d]
  u16* Wqkv = xbm + 4194304;           // 3M  [Wq|Wk|Wv], head-perm rows
  u16* Wob  = Wqkv + 3145728;          // 1M
  u16* Qh   = Wob + 1048576;           // 4M  [bh][t][64]
  u16* Kh   = Qh  + 4194304;           // 4M  [bh][t][64]
  u16* Vt   = Kh  + 4194304;           // 4M  [bh][64][t]
  u16* Aout = Vt  + 4194304;           // 4M  [b*2048+t][h*64+dp]

  cast_all<<<8192, 256, 0, stream>>>(x, Wk, Wv, Wq, Wo, ws);

  gemm_qkv<<<512, 256, 0, stream>>>(xbm, Wqkv, Qh, Kh, Vt);

  attn_fwd<<<512, 512, 0, stream>>>(Qh, Kh, Vt, Aout);

  gemm_o<<<512, 256, 0, stream>>>(Aout, Wob, (float*)d_out);
}